// Round 3
// baseline (277.271 us; speedup 1.0000x reference)
//
#include <hip/hip_runtime.h>
#include <hip/hip_bf16.h>
#include <hip/hip_fp16.h>

// Bahdanau location-sensitive attention, fused f16-MFMA implementation.
// R3: k_main = 256x256 tile, 4-phase-per-K-step schedule (m201-style T3+T4+T5):
//     per phase {issue VMEM, ds_read subtile, s_barrier, lgkm(0), 16 MFMA, s_barrier},
//     counted vmcnt (prefetch issued 2-3 phases before drain), B via global_load_lds
//     (linear dest + inverse-swizzled source), A reg-staged with f32->f16 cvt.
// B=32 T=1536 H=1024 CTX=1024 CONV_OUT=32

constexpr int kB = 32, kT = 1536, kH = 1024, kC = 1024, kCO = 32;
constexpr int kM = kB * kT;      // 49152
constexpr int kK = kH + kCO;     // 1056

typedef _Float16 f16;
typedef _Float16 f16x8 __attribute__((ext_vector_type(8)));
typedef float f32x4 __attribute__((ext_vector_type(4)));

// ---- ws layout (bytes) ----
constexpr size_t WS_BF16  = 0;                                  // kC*kK f16   (2.2 MB)
constexpr size_t WS_LOC   = WS_BF16 + (size_t)kC * kK * 2;      // kM*kCO f16  (3 MB)
constexpr size_t WS_ADD   = WS_LOC + (size_t)kM * kCO * 2;      // kB*kC f32
constexpr size_t WS_SCORE = WS_ADD + (size_t)kB * kC * 4;       // 4*kM f32 partial scores
constexpr size_t WS_CTXP  = WS_SCORE + (size_t)4 * kM * 4;      // 8*kB*kH f32

__device__ __forceinline__ void gload16(const void* g, void* l) {
    __builtin_amdgcn_global_load_lds(
        (const __attribute__((address_space(1))) void*)g,
        (__attribute__((address_space(3))) void*)l, 16, 0, 0);
}

// ---------------------------------------------------------------- prep B
__global__ void k_prep_b(const float* __restrict__ V, const float* __restrict__ U,
                         f16* __restrict__ Bf) {
    int idx = blockIdx.x * 256 + threadIdx.x;        // < kC*kK
    int c = idx / kK, k = idx - c * kK;
    float v = (k < kH) ? V[(size_t)c * kH + k] : U[(size_t)c * kCO + (k - kH)];
    Bf[idx] = (f16)v;
}

// ---------------------------------------------------------------- prep loc (conv1d)
__global__ void k_prep_loc(const float* __restrict__ la, const float* __restrict__ cw,
                           const float* __restrict__ cb, f16* __restrict__ loc) {
    int m = blockIdx.x * 256 + threadIdx.x;          // < kM
    int b = m / kT, t = m - b * kT;
    float x0 = (t > 0)      ? la[(size_t)b * kT + t - 1] : 0.f;
    float x1 = la[(size_t)b * kT + t];
    float x2 = (t < kT - 1) ? la[(size_t)b * kT + t + 1] : 0.f;
    union { f16 h[32]; int4 q[4]; } u;
#pragma unroll
    for (int k = 0; k < 32; ++k)
        u.h[k] = (f16)(cw[k * 3] * x0 + cw[k * 3 + 1] * x1 + cw[k * 3 + 2] * x2 + cb[k]);
    int4* dst = (int4*)(loc + (size_t)m * 32);
    dst[0] = u.q[0]; dst[1] = u.q[1]; dst[2] = u.q[2]; dst[3] = u.q[3];
}

// ---------------------------------------------------------------- prep add = dec@W^T + bias
__global__ void k_prep_add(const float* __restrict__ dec, const float* __restrict__ W,
                           const float* __restrict__ bias, float* __restrict__ add) {
    __shared__ float dl[kH];
    int bb = blockIdx.x >> 2;
    int cc = (blockIdx.x & 3) * 256 + threadIdx.x;
    *(float4*)&dl[threadIdx.x * 4] = *(const float4*)&dec[(size_t)bb * kH + threadIdx.x * 4];
    __syncthreads();
    float acc = bias[cc];
    const float* wr = W + (size_t)cc * kH;
    for (int h = 0; h < kH; h += 4) {
        float4 wv = *(const float4*)&wr[h];
        acc += wv.x * dl[h] + wv.y * dl[h + 1] + wv.z * dl[h + 2] + wv.w * dl[h + 3];
    }
    add[(size_t)bb * kC + cc] = acc;
}

// macros for the phase bodies -----------------------------------
#define RD_AF(mi2, MI) { const int row_ = wm * 128 + (MI) * 16 + rl;                         \
    af[mi2][0] = *(const f16x8*)(Ac + row_ * 128 + (((0 + g) ^ (row_ & 7)) * 16));           \
    af[mi2][1] = *(const f16x8*)(Ac + row_ * 128 + (((4 + g) ^ (row_ & 7)) * 16)); }

#define DO_MFMA_Q(Q)                                                                          \
    __builtin_amdgcn_s_setprio(1);                                                            \
    { _Pragma("unroll") for (int ni = 0; ni < 4; ++ni) {                                      \
        acc[2*(Q)][ni]   = __builtin_amdgcn_mfma_f32_16x16x32_f16(af[0][0], bfv[ni][0], acc[2*(Q)][ni],   0, 0, 0); \
        acc[2*(Q)][ni]   = __builtin_amdgcn_mfma_f32_16x16x32_f16(af[0][1], bfv[ni][1], acc[2*(Q)][ni],   0, 0, 0); \
        acc[2*(Q)+1][ni] = __builtin_amdgcn_mfma_f32_16x16x32_f16(af[1][0], bfv[ni][0], acc[2*(Q)+1][ni], 0, 0, 0); \
        acc[2*(Q)+1][ni] = __builtin_amdgcn_mfma_f32_16x16x32_f16(af[1][1], bfv[ni][1], acc[2*(Q)+1][ni], 0, 0, 0); } } \
    __builtin_amdgcn_s_setprio(0);

#define PHASE_BAR()                                                                           \
    __builtin_amdgcn_s_barrier();                                                             \
    asm volatile("s_waitcnt lgkmcnt(0)" ::: "memory");                                        \
    __builtin_amdgcn_sched_barrier(0);

// ---------------------------------------------------------------- fused main GEMM
// tile 256(M) x 256(N), 512 threads = 8 waves (2 x 4), per-wave 128x64, BK=64.
__launch_bounds__(512, 2)
__global__ void k_main(const float* __restrict__ enc, const f16* __restrict__ Bf,
                       const f16* __restrict__ loc, const float* __restrict__ add,
                       const float* __restrict__ wvec, float* __restrict__ spart) {
    // LDS: A[2][256*64 f16] @0 (2x32KB), B[2][...] @65536, add_l @131072, w_l @132096
    // sred aliases B[1] (@98304) — dead by epilogue time.
    __shared__ __align__(16) char smem[133120];
    float* add_l = (float*)(smem + 131072);
    float* w_l   = (float*)(smem + 132096);

    const int tid = threadIdx.x, lane = tid & 63, wave = tid >> 6;
    const int wm = wave >> 2, wn = wave & 3;
    // bijective XCD-chunked swizzle: 768 blocks, 8 XCDs, 96 blocks/XCD.
    const int raw = blockIdx.x;
    const int swz = (raw & 7) * 96 + (raw >> 3);
    const int mt = swz >> 2, nt = swz & 3;           // nt fastest: A strip shared in-XCD
    const int m0 = mt * 256, n0 = nt * 256;
    const int bb = m0 / kT;                          // 1536 % 256 == 0: one batch per tile

    if (tid < 256) {
        add_l[tid] = add[(size_t)bb * kC + n0 + tid];
        w_l[tid]   = wvec[n0 + tid];
    }

    f32x4 acc[8][4];
#pragma unroll
    for (int i = 0; i < 8; ++i)
#pragma unroll
        for (int j = 0; j < 4; ++j) acc[i][j] = (f32x4){0.f, 0.f, 0.f, 0.f};

    // A staging assignment: 2 threads/row, 32 f32 (8 float4) each
    const int srow = tid >> 1, shalf = tid & 1, sxm = srow & 7;
    const float* a_src  = enc + (size_t)(m0 + srow) * kH + shalf * 32;
    const f16*   l_src  = loc + (size_t)(m0 + srow) * kCO + shalf * 16;
    const f16*   bt_src = Bf  + (size_t)(n0 + srow) * kK + kH + shalf * 16;

    // B gload_lds lane sources: instruction j covers rows wave*32+j*8 .. +8
    // LDS linear dest (row, slot) <- global col-chunk (slot ^ (row&7))  [rule 21]
    const int brow0 = wave * 32 + (lane >> 3);
    const int bslot = lane & 7;
    const f16* bgl0 = Bf + (size_t)(n0 + brow0 +  0) * kK + ((bslot ^ ((brow0 +  0) & 7)) * 8);
    const f16* bgl1 = Bf + (size_t)(n0 + brow0 +  8) * kK + ((bslot ^ ((brow0 +  8) & 7)) * 8);
    const f16* bgl2 = Bf + (size_t)(n0 + brow0 + 16) * kK + ((bslot ^ ((brow0 + 16) & 7)) * 8);
    const f16* bgl3 = Bf + (size_t)(n0 + brow0 + 24) * kK + ((bslot ^ ((brow0 + 24) & 7)) * 8);

    float4 a_ld[8];
    int4 ta0, ta1, tb0, tb1;

    // ---- prologue: stage tile 0 into buf 0
#pragma unroll
    for (int q = 0; q < 8; ++q) a_ld[q] = *(const float4*)(a_src + q * 4);
    {
        char* B0 = smem + 65536 + wave * 4096;
        gload16(bgl0, B0);
        gload16(bgl1, B0 + 1024);
        gload16(bgl2, B0 + 2048);
        gload16(bgl3, B0 + 3072);
    }
    {
        union { f16 h[32]; int4 q[4]; } pk;
#pragma unroll
        for (int q = 0; q < 8; ++q) {
            pk.h[q * 4 + 0] = (f16)a_ld[q].x; pk.h[q * 4 + 1] = (f16)a_ld[q].y;
            pk.h[q * 4 + 2] = (f16)a_ld[q].z; pk.h[q * 4 + 3] = (f16)a_ld[q].w;
        }
        char* Aw = smem + srow * 128;
#pragma unroll
        for (int j = 0; j < 4; ++j)
            *(int4*)(Aw + (((shalf * 4 + j) ^ sxm) * 16)) = pk.q[j];
    }
    asm volatile("s_waitcnt vmcnt(0) lgkmcnt(0)" ::: "memory");
    __builtin_amdgcn_s_barrier();

    const int g = lane >> 4, rl = lane & 15;

    // ---- main loop: 16 K-steps of 64; tail (K=32: loc|U) staged during t==15
    for (int t = 0; t < 16; ++t) {
        const int cur = t & 1;
        const char* Ac = smem + cur * 32768;
        const char* Bc = smem + 65536 + cur * 32768;
        char* Awn = smem + (cur ^ 1) * 32768;
        char* Bwn = smem + 65536 + (cur ^ 1) * 32768 + wave * 4096;

        f16x8 bfv[4][2];
        f16x8 af[2][2];

        // ================= phase 0: issue A[0..3]+G0 (t+1), read B frags + A q0
        if (t < 15) {
            const int k0 = (t + 1) * 64;
#pragma unroll
            for (int q = 0; q < 4; ++q) a_ld[q] = *(const float4*)(a_src + k0 + q * 4);
            gload16(bgl0 + k0, Bwn);
        } else {
            ta0 = *(const int4*)(l_src);
            ta1 = *(const int4*)(l_src + 8);
            tb0 = *(const int4*)(bt_src);
            tb1 = *(const int4*)(bt_src + 8);
        }
#pragma unroll
        for (int ni = 0; ni < 4; ++ni) {
            const int row_ = wn * 64 + ni * 16 + rl;
            bfv[ni][0] = *(const f16x8*)(Bc + row_ * 128 + (((0 + g) ^ (row_ & 7)) * 16));
            bfv[ni][1] = *(const f16x8*)(Bc + row_ * 128 + (((4 + g) ^ (row_ & 7)) * 16));
        }
        RD_AF(0, 0) RD_AF(1, 1)
        PHASE_BAR()
        DO_MFMA_Q(0)
        __builtin_amdgcn_s_barrier();

        // ================= phase 1: issue A[4..7]+G1, read A q1
        if (t < 15) {
            const int k0 = (t + 1) * 64;
#pragma unroll
            for (int q = 4; q < 8; ++q) a_ld[q] = *(const float4*)(a_src + k0 + q * 4);
            gload16(bgl1 + k0, Bwn + 1024);
        }
        RD_AF(0, 2) RD_AF(1, 3)
        PHASE_BAR()
        DO_MFMA_Q(1)
        __builtin_amdgcn_s_barrier();

        // ================= phase 2: issue G2+G3, read A q2
        if (t < 15) {
            const int k0 = (t + 1) * 64;
            gload16(bgl2 + k0, Bwn + 2048);
            gload16(bgl3 + k0, Bwn + 3072);
        }
        RD_AF(0, 4) RD_AF(1, 5)
        PHASE_BAR()
        DO_MFMA_Q(2)
        __builtin_amdgcn_s_barrier();

        // ================= phase 3: read A q3, cvt+ds_write A(t+1), drain, MFMA q3
        RD_AF(0, 6) RD_AF(1, 7)
        if (t < 15) {
            union { f16 h[32]; int4 q[4]; } pk;
#pragma unroll
            for (int q = 0; q < 8; ++q) {
                pk.h[q * 4 + 0] = (f16)a_ld[q].x; pk.h[q * 4 + 1] = (f16)a_ld[q].y;
                pk.h[q * 4 + 2] = (f16)a_ld[q].z; pk.h[q * 4 + 3] = (f16)a_ld[q].w;
            }
            char* Aw = Awn + srow * 128;
#pragma unroll
            for (int j = 0; j < 4; ++j)
                *(int4*)(Aw + (((shalf * 4 + j) ^ sxm) * 16)) = pk.q[j];
        } else {
            char* Aw = Awn + srow * 128;
            char* Bw = Bwn - wave * 4096 + srow * 128;
            *(int4*)(Aw + (((shalf * 2 + 0) ^ sxm) * 16)) = ta0;
            *(int4*)(Aw + (((shalf * 2 + 1) ^ sxm) * 16)) = ta1;
            *(int4*)(Bw + (((shalf * 2 + 0) ^ sxm) * 16)) = tb0;
            *(int4*)(Bw + (((shalf * 2 + 1) ^ sxm) * 16)) = tb1;
        }
        // drain: B gloads (issued >=1 phase ago) + our ds_writes, then barrier
        asm volatile("s_waitcnt vmcnt(0) lgkmcnt(0)" ::: "memory");
        __builtin_amdgcn_s_barrier();
        __builtin_amdgcn_sched_barrier(0);
        DO_MFMA_Q(3)
        __builtin_amdgcn_s_barrier();
    }

    // ---- tail compute: buf 0, K=32 (slots 0..3 pre-xor)
    {
        const char* Ac = smem;
        const char* Bc = smem + 65536;
        f16x8 bt[4];
#pragma unroll
        for (int ni = 0; ni < 4; ++ni) {
            const int row_ = wn * 64 + ni * 16 + rl;
            bt[ni] = *(const f16x8*)(Bc + row_ * 128 + ((g ^ (row_ & 7)) * 16));
        }
        __builtin_amdgcn_s_setprio(1);
#pragma unroll
        for (int mi = 0; mi < 8; ++mi) {
            const int row_ = wm * 128 + mi * 16 + rl;
            f16x8 at = *(const f16x8*)(Ac + row_ * 128 + ((g ^ (row_ & 7)) * 16));
#pragma unroll
            for (int ni = 0; ni < 4; ++ni)
                acc[mi][ni] = __builtin_amdgcn_mfma_f32_16x16x32_f16(at, bt[ni], acc[mi][ni], 0, 0, 0);
        }
        __builtin_amdgcn_s_setprio(0);
    }

    // ---- epilogue: e = tanh(acc + add[c]); partial score = sum_c e*w[c]
    float (*sred)[128][4] = (float (*)[128][4])(smem + 98304);  // aliases B buf1 (dead)
    {
        const int gq = lane >> 4;
#pragma unroll
        for (int mi = 0; mi < 8; ++mi) {
#pragma unroll
            for (int i = 0; i < 4; ++i) {
                float p = 0.f;
#pragma unroll
                for (int ni = 0; ni < 4; ++ni) {
                    int cl = wn * 64 + ni * 16 + rl;
                    float e = tanhf(acc[mi][ni][i] + add_l[cl]);
                    p += e * w_l[cl];
                }
                p += __shfl_xor(p, 1);
                p += __shfl_xor(p, 2);
                p += __shfl_xor(p, 4);
                p += __shfl_xor(p, 8);
                if (rl == 0) sred[wm][mi * 16 + gq * 4 + i][wn] = p;
            }
        }
    }
    __syncthreads();
    if (tid < 256) {
        float s = sred[tid >> 7][tid & 127][0] + sred[tid >> 7][tid & 127][1]
                + sred[tid >> 7][tid & 127][2] + sred[tid >> 7][tid & 127][3];
        spart[(size_t)nt * kM + m0 + tid] = s;
    }
}

// ---------------------------------------------------------------- softmax over T
__global__ void k_softmax(const float* __restrict__ spart, float* __restrict__ out_align) {
    __shared__ float red[256];
    int b = blockIdx.x, tid = threadIdx.x;
    float v[6];
    float mx = -1e30f;
#pragma unroll
    for (int i = 0; i < 6; ++i) {
        size_t idx = (size_t)b * kT + tid + i * 256;
        float s = spart[idx] + spart[kM + idx] + spart[2 * (size_t)kM + idx] + spart[3 * (size_t)kM + idx];
        v[i] = s; mx = fmaxf(mx, s);
    }
    red[tid] = mx; __syncthreads();
    for (int o = 128; o > 0; o >>= 1) { if (tid < o) red[tid] = fmaxf(red[tid], red[tid + o]); __syncthreads(); }
    mx = red[0]; __syncthreads();
    float sum = 0.f;
#pragma unroll
    for (int i = 0; i < 6; ++i) { v[i] = expf(v[i] - mx); sum += v[i]; }
    red[tid] = sum; __syncthreads();
    for (int o = 128; o > 0; o >>= 1) { if (tid < o) red[tid] += red[tid + o]; __syncthreads(); }
    float inv = 1.f / red[0];
#pragma unroll
    for (int i = 0; i < 6; ++i)
        out_align[(size_t)b * kT + tid + i * 256] = v[i] * inv;
}

// ---------------------------------------------------------------- context partials
__global__ void k_ctx_part(const float* __restrict__ enc, const float* __restrict__ align,
                           float* __restrict__ cpart) {
    __shared__ float al[192];
    int ci = blockIdx.x, b = blockIdx.y, tid = threadIdx.x;
    if (tid < 192) al[tid] = align[(size_t)b * kT + ci * 192 + tid];
    __syncthreads();
    float4 acc = {0.f, 0.f, 0.f, 0.f};
    const float* ep = enc + ((size_t)b * kT + (size_t)ci * 192) * kH + tid * 4;
    for (int t = 0; t < 192; ++t) {
        float a = al[t];
        float4 e = *(const float4*)(ep + (size_t)t * kH);
        acc.x += a * e.x; acc.y += a * e.y; acc.z += a * e.z; acc.w += a * e.w;
    }
    *(float4*)&cpart[((size_t)ci * kB + b) * kH + tid * 4] = acc;
}

__global__ void k_ctx_red(const float* __restrict__ cpart, float* __restrict__ out_ctx) {
    int idx = blockIdx.x * 256 + threadIdx.x;   // < kB*kH
    float s = 0.f;
#pragma unroll
    for (int ci = 0; ci < 8; ++ci) s += cpart[(size_t)ci * kB * kH + idx];
    out_ctx[idx] = s;
}

// ---------------------------------------------------------------- launch
extern "C" void kernel_launch(void* const* d_in, const int* in_sizes, int n_in,
                              void* d_out, int out_size, void* d_ws, size_t ws_size,
                              hipStream_t stream) {
    const float* dec  = (const float*)d_in[0];
    const float* enc  = (const float*)d_in[1];
    const float* la   = (const float*)d_in[2];
    const float* W    = (const float*)d_in[3];
    const float* V    = (const float*)d_in[4];
    const float* U    = (const float*)d_in[5];
    const float* bias = (const float*)d_in[6];
    const float* wv   = (const float*)d_in[7];
    const float* cw   = (const float*)d_in[8];
    const float* cb   = (const float*)d_in[9];

    char* ws = (char*)d_ws;
    f16* Bf      = (f16*)(ws + WS_BF16);
    f16* loc     = (f16*)(ws + WS_LOC);
    float* add   = (float*)(ws + WS_ADD);
    float* spart = (float*)(ws + WS_SCORE);
    float* cpart = (float*)(ws + WS_CTXP);

    float* out_ctx   = (float*)d_out;            // (B,H)
    float* out_align = (float*)d_out + kB * kH;  // (B,T)

    hipLaunchKernelGGL(k_prep_b,   dim3(kC * kK / 256), dim3(256), 0, stream, V, U, Bf);
    hipLaunchKernelGGL(k_prep_loc, dim3(kM / 256),      dim3(256), 0, stream, la, cw, cb, loc);
    hipLaunchKernelGGL(k_prep_add, dim3(kB * 4),        dim3(256), 0, stream, dec, W, bias, add);
    hipLaunchKernelGGL(k_main,     dim3((kM / 256) * 4), dim3(512), 0, stream, enc, Bf, loc, add, wv, spart);
    hipLaunchKernelGGL(k_softmax,  dim3(kB),            dim3(256), 0, stream, spart, out_align);
    hipLaunchKernelGGL(k_ctx_part, dim3(8, kB),         dim3(256), 0, stream, enc, out_align, cpart);
    hipLaunchKernelGGL(k_ctx_red,  dim3(kB * kH / 256), dim3(256), 0, stream, cpart, out_ctx);
}

// Round 4
// 266.180 us; speedup vs baseline: 1.0417x; 1.0417x over previous
//
#include <hip/hip_runtime.h>
#include <hip/hip_bf16.h>
#include <hip/hip_fp16.h>

// Bahdanau location-sensitive attention, fused f16-MFMA implementation.
// R4: pre-convert enc -> f16 packed A [M][1088] (loc appended, zero pad), then
//     k_main = faithful m201 clone: BOTH operands via global_load_lds(16),
//     4 phases/K-tile, front-loaded staging, boundary vmcnt drain with slack.
//     Fallback to R1 path if ws_size too small.
// B=32 T=1536 H=1024 CTX=1024 CONV_OUT=32

constexpr int kB = 32, kT = 1536, kH = 1024, kC = 1024, kCO = 32;
constexpr int kM = kB * kT;      // 49152
constexpr int kKp = 1088;        // padded K: 1024 enc | 32 loc | 32 zero
constexpr int kKf = 1056;        // fallback K (1024|32)

typedef _Float16 f16;
typedef _Float16 f16x8 __attribute__((ext_vector_type(8)));
typedef float f32x4 __attribute__((ext_vector_type(4)));

// ---- primary ws layout (bytes) ----
constexpr size_t W2_A     = 0;                                   // kM*kKp f16 = 106.95 MB
constexpr size_t W2_B     = W2_A + (size_t)kM * kKp * 2;         // kC*kKp f16 = 2.23 MB
constexpr size_t W2_ADD   = W2_B + (size_t)kC * kKp * 2;         // kB*kC f32
constexpr size_t W2_SCORE = W2_ADD + (size_t)kB * kC * 4;        // 4*kM f32
constexpr size_t W2_CTXP  = W2_SCORE + (size_t)4 * kM * 4;       // 8*kB*kH f32
constexpr size_t W2_NEED  = W2_CTXP + (size_t)8 * kB * kH * 4;   // ~111.1 MB

// ---- fallback ws layout (bytes) ----
constexpr size_t WF_B     = 0;                                   // kC*kKf f16
constexpr size_t WF_LOC   = WF_B + (size_t)kC * kKf * 2;         // kM*kCO f16
constexpr size_t WF_ADD   = WF_LOC + (size_t)kM * kCO * 2;
constexpr size_t WF_SCORE = WF_ADD + (size_t)kB * kC * 4;
constexpr size_t WF_CTXP  = WF_SCORE + (size_t)4 * kM * 4;

__device__ __forceinline__ void gload16(const void* g, void* l) {
    __builtin_amdgcn_global_load_lds(
        (const __attribute__((address_space(1))) void*)g,
        (__attribute__((address_space(3))) void*)l, 16, 0, 0);
}

// ================================================================ primary path
// ---------------------------------------------------------------- cvt enc -> A f16
__global__ void k_cvt(const float* __restrict__ enc, f16* __restrict__ Af) {
    int gid = blockIdx.x * 256 + threadIdx.x;       // < kM*kH/8
    int row = gid >> 7, c8 = gid & 127;
    const float* src = enc + (size_t)row * kH + c8 * 8;
    float4 e0 = *(const float4*)src;
    float4 e1 = *(const float4*)(src + 4);
    union { f16 h[8]; int4 q; } u;
    u.h[0] = (f16)e0.x; u.h[1] = (f16)e0.y; u.h[2] = (f16)e0.z; u.h[3] = (f16)e0.w;
    u.h[4] = (f16)e1.x; u.h[5] = (f16)e1.y; u.h[6] = (f16)e1.z; u.h[7] = (f16)e1.w;
    *(int4*)(Af + (size_t)row * kKp + c8 * 8) = u.q;
}

// ---------------------------------------------------------------- loc (conv1d) -> A cols 1024..1087
__global__ void k_loc(const float* __restrict__ la, const float* __restrict__ cw,
                      const float* __restrict__ cb, f16* __restrict__ Af) {
    int m = blockIdx.x * 256 + threadIdx.x;          // < kM
    int b = m / kT, t = m - b * kT;
    float x0 = (t > 0)      ? la[(size_t)b * kT + t - 1] : 0.f;
    float x1 = la[(size_t)b * kT + t];
    float x2 = (t < kT - 1) ? la[(size_t)b * kT + t + 1] : 0.f;
    union { f16 h[32]; int4 q[4]; } u;
#pragma unroll
    for (int k = 0; k < 32; ++k)
        u.h[k] = (f16)(cw[k * 3] * x0 + cw[k * 3 + 1] * x1 + cw[k * 3 + 2] * x2 + cb[k]);
    int4* dst = (int4*)(Af + (size_t)m * kKp + kH);
    dst[0] = u.q[0]; dst[1] = u.q[1]; dst[2] = u.q[2]; dst[3] = u.q[3];
    int4 z = {0, 0, 0, 0};
    dst[4] = z; dst[5] = z; dst[6] = z; dst[7] = z;   // pad cols 1056..1087
}

// ---------------------------------------------------------------- B pack [kC][1088]
__global__ void k_prep_b2(const float* __restrict__ V, const float* __restrict__ U,
                          f16* __restrict__ Bf) {
    int c = blockIdx.x;
    for (int k = threadIdx.x; k < kKp; k += 256) {
        float v = (k < kH) ? V[(size_t)c * kH + k]
                : (k < kH + kCO) ? U[(size_t)c * kCO + (k - kH)] : 0.f;
        Bf[(size_t)c * kKp + k] = (f16)v;
    }
}

// ---------------------------------------------------------------- prep add = dec@W^T + bias
__global__ void k_prep_add(const float* __restrict__ dec, const float* __restrict__ W,
                           const float* __restrict__ bias, float* __restrict__ add) {
    __shared__ float dl[kH];
    int bb = blockIdx.x >> 2;
    int cc = (blockIdx.x & 3) * 256 + threadIdx.x;
    *(float4*)&dl[threadIdx.x * 4] = *(const float4*)&dec[(size_t)bb * kH + threadIdx.x * 4];
    __syncthreads();
    float acc = bias[cc];
    const float* wr = W + (size_t)cc * kH;
    for (int h = 0; h < kH; h += 4) {
        float4 wv = *(const float4*)&wr[h];
        acc += wv.x * dl[h] + wv.y * dl[h + 1] + wv.z * dl[h + 2] + wv.w * dl[h + 3];
    }
    add[(size_t)bb * kC + cc] = acc;
}

// phase helpers --------------------------------------------------
#define RD_A2(x, MI) { const int row_ = wm * 128 + (MI) * 16 + rl;                            \
    af[x][0] = *(const f16x8*)(Ac + row_ * 128 + (((0 + g) ^ (rl & 7)) * 16));                \
    af[x][1] = *(const f16x8*)(Ac + row_ * 128 + (((4 + g) ^ (rl & 7)) * 16)); }

#define MFMA_Q(Q)                                                                             \
    __builtin_amdgcn_s_setprio(1);                                                            \
    { _Pragma("unroll") for (int ni = 0; ni < 4; ++ni) {                                      \
        acc[2*(Q)][ni]   = __builtin_amdgcn_mfma_f32_16x16x32_f16(af[0][0], bfv[ni][0], acc[2*(Q)][ni],   0, 0, 0); \
        acc[2*(Q)][ni]   = __builtin_amdgcn_mfma_f32_16x16x32_f16(af[0][1], bfv[ni][1], acc[2*(Q)][ni],   0, 0, 0); \
        acc[2*(Q)+1][ni] = __builtin_amdgcn_mfma_f32_16x16x32_f16(af[1][0], bfv[ni][0], acc[2*(Q)+1][ni], 0, 0, 0); \
        acc[2*(Q)+1][ni] = __builtin_amdgcn_mfma_f32_16x16x32_f16(af[1][1], bfv[ni][1], acc[2*(Q)+1][ni], 0, 0, 0); } } \
    __builtin_amdgcn_s_setprio(0);

#define PBAR()                                                                                \
    __builtin_amdgcn_s_barrier();                                                             \
    asm volatile("s_waitcnt lgkmcnt(0)" ::: "memory");                                        \
    __builtin_amdgcn_sched_barrier(0);

// ---------------------------------------------------------------- fused main GEMM (m201 clone)
// 256x256 tile, BK=64, 512 thr = 8 waves (2M x 4N), per-wave 128x64.
// LDS: buf[c]: A @ c*65536, B @ c*65536+32768; add_l @131072, w_l @132096.
__launch_bounds__(512, 2)
__global__ void k_main(const f16* __restrict__ Ag, const f16* __restrict__ Bg,
                       const float* __restrict__ add, const float* __restrict__ wvec,
                       float* __restrict__ spart) {
    __shared__ __align__(16) char smem[133120];
    float* add_l = (float*)(smem + 131072);
    float* w_l   = (float*)(smem + 132096);

    const int tid = threadIdx.x, lane = tid & 63, wave = tid >> 6;
    const int wm = wave >> 2, wn = wave & 3;
    const int raw = blockIdx.x;                       // 768 = 8 XCDs x 96
    const int swz = (raw & 7) * 96 + (raw >> 3);
    const int mt = swz >> 2, nt = swz & 3;            // nt fastest: A strip reuse in-XCD
    const int m0 = mt * 256, n0 = nt * 256;
    const int bb = m0 / kT;

    if (tid < 256) {
        add_l[tid] = add[(size_t)bb * kC + n0 + tid];
        w_l[tid]   = wvec[n0 + tid];
    }

    f32x4 acc[8][4];
#pragma unroll
    for (int i = 0; i < 8; ++i)
#pragma unroll
        for (int j = 0; j < 4; ++j) acc[i][j] = (f32x4){0.f, 0.f, 0.f, 0.f};

    // gload lane mapping: instr j covers 8 rows (wave*32 + j*8), lane>>3 = row-in-group,
    // lane&7 = LDS slot; global col chunk = slot ^ (row&7) = (lane&7) ^ (lane>>3).
    const int srow8 = lane >> 3;
    const int sslot = (lane & 7) ^ srow8;
    const f16* aSrc[4]; const f16* bSrc[4];
#pragma unroll
    for (int j = 0; j < 4; ++j) {
        aSrc[j] = Ag + (size_t)(m0 + wave * 32 + j * 8 + srow8) * kKp + sslot * 8;
        bSrc[j] = Bg + (size_t)(n0 + wave * 32 + j * 8 + srow8) * kKp + sslot * 8;
    }
    const int ldsOff = (wave * 32) * 128;             // within A or B region

    // ---- prologue: stage K-tile 0 into buf 0
#pragma unroll
    for (int j = 0; j < 4; ++j) gload16(aSrc[j], smem + ldsOff + j * 1024);
#pragma unroll
    for (int j = 0; j < 4; ++j) gload16(bSrc[j], smem + 32768 + ldsOff + j * 1024);
    asm volatile("s_waitcnt vmcnt(0) lgkmcnt(0)" ::: "memory");
    __builtin_amdgcn_s_barrier();

    const int g = lane >> 4, rl = lane & 15;

    for (int t = 0; t < 17; ++t) {
        const int cur = t & 1;
        const char* Ac = smem + cur * 65536;
        const char* Bc = smem + cur * 65536 + 32768;
        char* An = smem + (cur ^ 1) * 65536 + ldsOff;
        char* Bn = smem + (cur ^ 1) * 65536 + 32768 + ldsOff;
        const size_t knxt = (size_t)(t + 1) * 64;

        f16x8 bfv[4][2], af[2][2];

        // ===== phase 0: stage A(t+1) x4; read B frags (8) + A q0 (4)
        if (t < 16) {
#pragma unroll
            for (int j = 0; j < 4; ++j) gload16(aSrc[j] + knxt, An + j * 1024);
        }
#pragma unroll
        for (int ni = 0; ni < 4; ++ni) {
            const int row_ = wn * 64 + ni * 16 + rl;
            bfv[ni][0] = *(const f16x8*)(Bc + row_ * 128 + (((0 + g) ^ (rl & 7)) * 16));
            bfv[ni][1] = *(const f16x8*)(Bc + row_ * 128 + (((4 + g) ^ (rl & 7)) * 16));
        }
        RD_A2(0, 0) RD_A2(1, 1)
        asm volatile("s_waitcnt lgkmcnt(8)" ::: "memory");
        PBAR()
        MFMA_Q(0)
        __builtin_amdgcn_s_barrier();

        // ===== phase 1: stage B(t+1) x4; read A q1
        if (t < 16) {
#pragma unroll
            for (int j = 0; j < 4; ++j) gload16(bSrc[j] + knxt, Bn + j * 1024);
        }
        RD_A2(0, 2) RD_A2(1, 3)
        PBAR()
        MFMA_Q(1)
        __builtin_amdgcn_s_barrier();

        // ===== phase 2: read A q2
        RD_A2(0, 4) RD_A2(1, 5)
        PBAR()
        MFMA_Q(2)
        __builtin_amdgcn_s_barrier();

        // ===== phase 3: read A q3; MFMA; drain next-tile loads (~2 phases slack); bar
        RD_A2(0, 6) RD_A2(1, 7)
        PBAR()
        MFMA_Q(3)
        asm volatile("s_waitcnt vmcnt(0)" ::: "memory");
        __builtin_amdgcn_s_barrier();
    }

    // ---- epilogue: e = tanh(acc + add[c]); partial score = sum_c e*w[c]
    float (*sred)[128][4] = (float (*)[128][4])(smem + 65536);   // buf1 A region (dead)
    {
        const int gq = lane >> 4;
#pragma unroll
        for (int mi = 0; mi < 8; ++mi) {
#pragma unroll
            for (int i = 0; i < 4; ++i) {
                float p = 0.f;
#pragma unroll
                for (int ni = 0; ni < 4; ++ni) {
                    int cl = wn * 64 + ni * 16 + rl;
                    float e = tanhf(acc[mi][ni][i] + add_l[cl]);
                    p += e * w_l[cl];
                }
                p += __shfl_xor(p, 1);
                p += __shfl_xor(p, 2);
                p += __shfl_xor(p, 4);
                p += __shfl_xor(p, 8);
                if (rl == 0) sred[wm][mi * 16 + gq * 4 + i][wn] = p;
            }
        }
    }
    __syncthreads();
    if (tid < 256) {
        float s = sred[tid >> 7][tid & 127][0] + sred[tid >> 7][tid & 127][1]
                + sred[tid >> 7][tid & 127][2] + sred[tid >> 7][tid & 127][3];
        spart[(size_t)nt * kM + m0 + tid] = s;
    }
}

// ================================================================ fallback path (R1, proven)
__global__ void k_prep_b_fb(const float* __restrict__ V, const float* __restrict__ U,
                            f16* __restrict__ Bf) {
    int idx = blockIdx.x * 256 + threadIdx.x;
    int c = idx / kKf, k = idx - c * kKf;
    float v = (k < kH) ? V[(size_t)c * kH + k] : U[(size_t)c * kCO + (k - kH)];
    Bf[idx] = (f16)v;
}

__global__ void k_loc_fb(const float* __restrict__ la, const float* __restrict__ cw,
                         const float* __restrict__ cb, f16* __restrict__ loc) {
    int m = blockIdx.x * 256 + threadIdx.x;
    int b = m / kT, t = m - b * kT;
    float x0 = (t > 0)      ? la[(size_t)b * kT + t - 1] : 0.f;
    float x1 = la[(size_t)b * kT + t];
    float x2 = (t < kT - 1) ? la[(size_t)b * kT + t + 1] : 0.f;
    union { f16 h[32]; int4 q[4]; } u;
#pragma unroll
    for (int k = 0; k < 32; ++k)
        u.h[k] = (f16)(cw[k * 3] * x0 + cw[k * 3 + 1] * x1 + cw[k * 3 + 2] * x2 + cb[k]);
    int4* dst = (int4*)(loc + (size_t)m * 32);
    dst[0] = u.q[0]; dst[1] = u.q[1]; dst[2] = u.q[2]; dst[3] = u.q[3];
}

__launch_bounds__(512)
__global__ void k_main_fb(const float* __restrict__ enc, const f16* __restrict__ Bf,
                          const f16* __restrict__ loc, const float* __restrict__ add,
                          const float* __restrict__ wvec, float* __restrict__ spart) {
    __shared__ __align__(16) f16 As[128 * 64];
    __shared__ __align__(16) f16 Bs[256 * 64];
    __shared__ float add_l[256], w_l[256];
    __shared__ float sred[2][64][4];

    const int tid = threadIdx.x, lane = tid & 63, wave = tid >> 6;
    const int wm = wave >> 2, wn = wave & 3;
    const int mt = blockIdx.x >> 2, nt = blockIdx.x & 3;
    const int m0 = mt * 128, n0 = nt * 256;
    const int bb = m0 / kT;

    if (tid < 256) {
        add_l[tid] = add[(size_t)bb * kC + n0 + tid];
        w_l[tid]   = wvec[n0 + tid];
    }

    f32x4 acc[4][4];
#pragma unroll
    for (int i = 0; i < 4; ++i)
#pragma unroll
        for (int j = 0; j < 4; ++j) acc[i][j] = (f32x4){0.f, 0.f, 0.f, 0.f};

    const int ar = tid >> 2, aq = tid & 3;
    const int br = tid >> 1, bh = tid & 1;
    const float* ap = enc + (size_t)(m0 + ar) * kH + aq * 16;
    const f16*   bp = Bf + (size_t)(n0 + br) * kKf;
    char* aw = (char*)As + ar * 128;
    char* bw = (char*)Bs + br * 128;
    const int axm = ar & 7, bxm = br & 7;

    for (int step = 0; step < 17; ++step) {
        if (step < 16) {
            const int k0 = step * 64;
            float4 f0 = *(const float4*)(ap + k0);
            float4 f1 = *(const float4*)(ap + k0 + 4);
            float4 f2 = *(const float4*)(ap + k0 + 8);
            float4 f3 = *(const float4*)(ap + k0 + 12);
            union { f16 h[16]; int4 q[2]; } pk;
            pk.h[0] = (f16)f0.x;  pk.h[1] = (f16)f0.y;  pk.h[2] = (f16)f0.z;  pk.h[3] = (f16)f0.w;
            pk.h[4] = (f16)f1.x;  pk.h[5] = (f16)f1.y;  pk.h[6] = (f16)f1.z;  pk.h[7] = (f16)f1.w;
            pk.h[8] = (f16)f2.x;  pk.h[9] = (f16)f2.y;  pk.h[10] = (f16)f2.z; pk.h[11] = (f16)f2.w;
            pk.h[12] = (f16)f3.x; pk.h[13] = (f16)f3.y; pk.h[14] = (f16)f3.z; pk.h[15] = (f16)f3.w;
            *(int4*)(aw + (((aq * 2 + 0) ^ axm) * 16)) = pk.q[0];
            *(int4*)(aw + (((aq * 2 + 1) ^ axm) * 16)) = pk.q[1];
            const char* bs = (const char*)(bp + k0 + bh * 32);
#pragma unroll
            for (int j = 0; j < 4; ++j) {
                int4 v = *(const int4*)(bs + j * 16);
                *(int4*)(bw + (((bh * 4 + j) ^ bxm) * 16)) = v;
            }
        } else {
            int4 v = *(const int4*)(loc + (size_t)(m0 + ar) * 32 + aq * 8);
            *(int4*)(aw + ((aq ^ axm) * 16)) = v;
#pragma unroll
            for (int j = 0; j < 2; ++j) {
                int4 w0 = *(const int4*)(bp + kH + (bh * 2 + j) * 8);
                *(int4*)(bw + (((bh * 2 + j) ^ bxm) * 16)) = w0;
            }
        }
        __syncthreads();
        const int nkk = (step < 16) ? 2 : 1;
        for (int kk = 0; kk < nkk; ++kk) {
            f16x8 af[4], bfr[4];
            const int g = lane >> 4, rl = lane & 15;
#pragma unroll
            for (int mi = 0; mi < 4; ++mi) {
                int row = wm * 64 + mi * 16 + rl;
                af[mi] = *(const f16x8*)((const char*)As + row * 128 + (((kk * 4 + g) ^ (row & 7)) * 16));
            }
#pragma unroll
            for (int ni = 0; ni < 4; ++ni) {
                int row = wn * 64 + ni * 16 + rl;
                bfr[ni] = *(const f16x8*)((const char*)Bs + row * 128 + (((kk * 4 + g) ^ (row & 7)) * 16));
            }
#pragma unroll
            for (int mi = 0; mi < 4; ++mi)
#pragma unroll
                for (int ni = 0; ni < 4; ++ni)
                    acc[mi][ni] = __builtin_amdgcn_mfma_f32_16x16x32_f16(af[mi], bfr[ni], acc[mi][ni], 0, 0, 0);
        }
        __syncthreads();
    }

#pragma unroll
    for (int mi = 0; mi < 4; ++mi) {
#pragma unroll
        for (int i = 0; i < 4; ++i) {
            float p = 0.f;
#pragma unroll
            for (int ni = 0; ni < 4; ++ni) {
                int cl = wn * 64 + ni * 16 + (lane & 15);
                float e = tanhf(acc[mi][ni][i] + add_l[cl]);
                p += e * w_l[cl];
            }
            p += __shfl_xor(p, 1);
            p += __shfl_xor(p, 2);
            p += __shfl_xor(p, 4);
            p += __shfl_xor(p, 8);
            if ((lane & 15) == 0)
                sred[wm][mi * 16 + (lane >> 4) * 4 + i][wn] = p;
        }
    }
    __syncthreads();
    if (tid < 128) {
        int r = tid & 63, w2 = tid >> 6;
        float s = sred[w2][r][0] + sred[w2][r][1] + sred[w2][r][2] + sred[w2][r][3];
        spart[(size_t)nt * kM + m0 + tid] = s;
    }
}

// ================================================================ shared epilogue kernels
__global__ void k_softmax(const float* __restrict__ spart, float* __restrict__ out_align) {
    __shared__ float red[256];
    int b = blockIdx.x, tid = threadIdx.x;
    float v[6];
    float mx = -1e30f;
#pragma unroll
    for (int i = 0; i < 6; ++i) {
        size_t idx = (size_t)b * kT + tid + i * 256;
        float s = spart[idx] + spart[kM + idx] + spart[2 * (size_t)kM + idx] + spart[3 * (size_t)kM + idx];
        v[i] = s; mx = fmaxf(mx, s);
    }
    red[tid] = mx; __syncthreads();
    for (int o = 128; o > 0; o >>= 1) { if (tid < o) red[tid] = fmaxf(red[tid], red[tid + o]); __syncthreads(); }
    mx = red[0]; __syncthreads();
    float sum = 0.f;
#pragma unroll
    for (int i = 0; i < 6; ++i) { v[i] = expf(v[i] - mx); sum += v[i]; }
    red[tid] = sum; __syncthreads();
    for (int o = 128; o > 0; o >>= 1) { if (tid < o) red[tid] += red[tid + o]; __syncthreads(); }
    float inv = 1.f / red[0];
#pragma unroll
    for (int i = 0; i < 6; ++i)
        out_align[(size_t)b * kT + tid + i * 256] = v[i] * inv;
}

__global__ void k_ctx_part(const float* __restrict__ enc, const float* __restrict__ align,
                           float* __restrict__ cpart) {
    __shared__ float al[192];
    int ci = blockIdx.x, b = blockIdx.y, tid = threadIdx.x;
    if (tid < 192) al[tid] = align[(size_t)b * kT + ci * 192 + tid];
    __syncthreads();
    float4 acc = {0.f, 0.f, 0.f, 0.f};
    const float* ep = enc + ((size_t)b * kT + (size_t)ci * 192) * kH + tid * 4;
    for (int t = 0; t < 192; ++t) {
        float a = al[t];
        float4 e = *(const float4*)(ep + (size_t)t * kH);
        acc.x += a * e.x; acc.y += a * e.y; acc.z += a * e.z; acc.w += a * e.w;
    }
    *(float4*)&cpart[((size_t)ci * kB + b) * kH + tid * 4] = acc;
}

__global__ void k_ctx_red(const float* __restrict__ cpart, float* __restrict__ out_ctx) {
    int idx = blockIdx.x * 256 + threadIdx.x;
    float s = 0.f;
#pragma unroll
    for (int ci = 0; ci < 8; ++ci) s += cpart[(size_t)ci * kB * kH + idx];
    out_ctx[idx] = s;
}

// ---------------------------------------------------------------- launch
extern "C" void kernel_launch(void* const* d_in, const int* in_sizes, int n_in,
                              void* d_out, int out_size, void* d_ws, size_t ws_size,
                              hipStream_t stream) {
    const float* dec  = (const float*)d_in[0];
    const float* enc  = (const float*)d_in[1];
    const float* la   = (const float*)d_in[2];
    const float* W    = (const float*)d_in[3];
    const float* V    = (const float*)d_in[4];
    const float* U    = (const float*)d_in[5];
    const float* bias = (const float*)d_in[6];
    const float* wv   = (const float*)d_in[7];
    const float* cw   = (const float*)d_in[8];
    const float* cb   = (const float*)d_in[9];

    char* ws = (char*)d_ws;
    float* out_ctx   = (float*)d_out;            // (B,H)
    float* out_align = (float*)d_out + kB * kH;  // (B,T)

    if (ws_size >= W2_NEED) {
        f16* Af      = (f16*)(ws + W2_A);
        f16* Bf      = (f16*)(ws + W2_B);
        float* add   = (float*)(ws + W2_ADD);
        float* spart = (float*)(ws + W2_SCORE);
        float* cpart = (float*)(ws + W2_CTXP);

        hipLaunchKernelGGL(k_prep_b2, dim3(kC),             dim3(256), 0, stream, V, U, Bf);
        hipLaunchKernelGGL(k_loc,     dim3(kM / 256),       dim3(256), 0, stream, la, cw, cb, Af);
        hipLaunchKernelGGL(k_cvt,     dim3(kM * kH / 8 / 256), dim3(256), 0, stream, enc, Af);
        hipLaunchKernelGGL(k_prep_add, dim3(kB * 4),        dim3(256), 0, stream, dec, W, bias, add);
        hipLaunchKernelGGL(k_main,    dim3((kM / 256) * 4), dim3(512), 0, stream, Af, Bf, add, wv, spart);
        hipLaunchKernelGGL(k_softmax, dim3(kB),             dim3(256), 0, stream, spart, out_align);
        hipLaunchKernelGGL(k_ctx_part, dim3(8, kB),         dim3(256), 0, stream, enc, out_align, cpart);
        hipLaunchKernelGGL(k_ctx_red, dim3(kB * kH / 256),  dim3(256), 0, stream, cpart, out_ctx);
    } else {
        f16* Bf      = (f16*)(ws + WF_B);
        f16* loc     = (f16*)(ws + WF_LOC);
        float* add   = (float*)(ws + WF_ADD);
        float* spart = (float*)(ws + WF_SCORE);
        float* cpart = (float*)(ws + WF_CTXP);

        hipLaunchKernelGGL(k_prep_b_fb, dim3(kC * kKf / 256), dim3(256), 0, stream, V, U, Bf);
        hipLaunchKernelGGL(k_loc_fb,  dim3(kM / 256),       dim3(256), 0, stream, la, cw, cb, loc);
        hipLaunchKernelGGL(k_prep_add, dim3(kB * 4),        dim3(256), 0, stream, dec, W, bias, add);
        hipLaunchKernelGGL(k_main_fb, dim3((kM / 128) * 4), dim3(512), 0, stream, enc, Bf, loc, add, wv, spart);
        hipLaunchKernelGGL(k_softmax, dim3(kB),             dim3(256), 0, stream, spart, out_align);
        hipLaunchKernelGGL(k_ctx_part, dim3(8, kB),         dim3(256), 0, stream, enc, out_align, cpart);
        hipLaunchKernelGGL(k_ctx_red, dim3(kB * kH / 256),  dim3(256), 0, stream, cpart, out_ctx);
    }
}